// Round 3
// baseline (498.795 us; speedup 1.0000x reference)
//
#include <hip/hip_runtime.h>
#include <hip/hip_bf16.h>
#include <math.h>

#define B_     4
#define S_     2048
#define D_     1024
#define INNER_ 64
#define M_     (B_ * S_)   // 8192 rows total

typedef __attribute__((ext_vector_type(8))) short short8v;  // 8 bf16 (4 VGPRs)
typedef __attribute__((ext_vector_type(4))) float f32x4;    // MFMA accumulator

__device__ __forceinline__ unsigned short f32_to_bf16_rne(float f) {
    unsigned u = __float_as_uint(f);
    unsigned r = (u + 0x7FFFu + ((u >> 16) & 1u)) >> 16;
    return (unsigned short)r;
}
__device__ __forceinline__ float bf16_to_f32(unsigned short h) {
    return __uint_as_float((unsigned)h << 16);
}

// ---------------------------------------------------------------------------
// Kernel A: out = seq @ W^T + bias  (M=8192, N=256, K=1024) in fp32, then
// RoPE; emit q/k as bf16 hi/lo planes: layout [m][head(2)][plane(2)][d(64)],
// 256 bf16 (512 B) per row. plane 0 = bf16(x), plane 1 = bf16(x - hi).
// 64x64 tile, BK=16, 4x4 register tile per thread, 256 threads.
// ---------------------------------------------------------------------------
__global__ __launch_bounds__(256)
void gemm1_rope_kernel(const float* __restrict__ seq, const float* __restrict__ W,
                       const float* __restrict__ bias,
                       unsigned short* __restrict__ qhl, unsigned short* __restrict__ khl) {
    const int bm = blockIdx.x;   // 128 tiles of 64 rows
    const int bn = blockIdx.y;   // 4 tiles of 64 cols (N=256)
    __shared__ float As[16][65];   // [k][m], +1 pad
    __shared__ float Bs[16][65];   // [k][n]
    __shared__ float s_inv[32];    // 15^(-i/32) table

    const int tid = threadIdx.x;
    if (tid < 32) s_inv[tid] = powf(15.0f, -(float)tid / 32.0f);

    const int tr = tid >> 4;    // 0..15
    const int tc = tid & 15;    // 0..15
    const int row0 = bm * 64, col0 = bn * 64;

    const int lr = tid >> 2;        // 0..63 (row within tile for staging)
    const int lc = (tid & 3) * 4;   // 0,4,8,12 (k-col within tile)

    float acc[4][4] = {};

    for (int k0 = 0; k0 < D_; k0 += 16) {
        float4 av = *reinterpret_cast<const float4*>(&seq[(size_t)(row0 + lr) * D_ + k0 + lc]);
        float4 bv = *reinterpret_cast<const float4*>(&W  [(size_t)(col0 + lr) * D_ + k0 + lc]);
        As[lc + 0][lr] = av.x; As[lc + 1][lr] = av.y; As[lc + 2][lr] = av.z; As[lc + 3][lr] = av.w;
        Bs[lc + 0][lr] = bv.x; Bs[lc + 1][lr] = bv.y; Bs[lc + 2][lr] = bv.z; Bs[lc + 3][lr] = bv.w;
        __syncthreads();
#pragma unroll
        for (int kk = 0; kk < 16; ++kk) {
            float a[4], b[4];
#pragma unroll
            for (int i = 0; i < 4; ++i) a[i] = As[kk][tr * 4 + i];
#pragma unroll
            for (int j = 0; j < 4; ++j) b[j] = Bs[kk][tc * 4 + j];
#pragma unroll
            for (int i = 0; i < 4; ++i)
#pragma unroll
                for (int j = 0; j < 4; ++j)
                    acc[i][j] = fmaf(a[i], b[j], acc[i][j]);
        }
        __syncthreads();
    }

    // Epilogue: bias + RoPE + hi/lo split + scatter to qhl/khl.
    // j layout: h = j>>7, c = j&127; c<64 -> q[d=c], else k[d=c-64].
#pragma unroll
    for (int i = 0; i < 4; ++i) {
        const int m = row0 + tr * 4 + i;
        const int s = m & (S_ - 1);
#pragma unroll
        for (int jj = 0; jj < 4; jj += 2) {
            const int j = col0 + tc * 4 + jj;
            const float x0 = acc[i][jj]     + bias[j];
            const float x1 = acc[i][jj + 1] + bias[j + 1];
            const int h = j >> 7;
            const int c = j & 127;
            const int d = c & 63;
            const float inv = s_inv[d >> 1];
            const float ang = (float)s * inv;
            float sn, cs;
            __sincosf(ang, &sn, &cs);
            const float r0 = x0 * cs - x1 * sn;
            const float r1 = x1 * cs + x0 * sn;
            unsigned short* dst = (c < 64) ? qhl : khl;
            // hi plane
            const unsigned short h0 = f32_to_bf16_rne(r0);
            const unsigned short h1 = f32_to_bf16_rne(r1);
            // lo plane (residual)
            const unsigned short l0 = f32_to_bf16_rne(r0 - bf16_to_f32(h0));
            const unsigned short l1 = f32_to_bf16_rne(r1 - bf16_to_f32(h1));
            const size_t base = (size_t)m * 256 + (size_t)h * 128 + d;
            *reinterpret_cast<ushort2*>(&dst[base])      = make_ushort2(h0, h1);
            *reinterpret_cast<ushort2*>(&dst[base + 64]) = make_ushort2(l0, l1);
        }
    }
}

// ---------------------------------------------------------------------------
// Kernel B (MFMA): pred_logits[b,m,n,h] = (q[b,m,h,:]·k[b,n,h,:]) * sim[b,m,n]
// via bf16 hi/lo split: q·k = qh·kh + qh·kl + ql·kh (fp32 MFMA accumulate).
// Block = 64(m) x 64(n) tile, 4 waves; wave w owns m-rows [w*16, w*16+16).
// Q fragments loaded directly from global (L2/L3-resident, 8 MB total);
// K tile staged in LDS with 528 B row stride (bank-conflict-free).
// Fused epilogue: sim scale, logits write, log-softmax NLL, block atomic.
// ---------------------------------------------------------------------------
__global__ __launch_bounds__(256)
void qk_loss_kernel(const unsigned short* __restrict__ qhl,
                    const unsigned short* __restrict__ khl,
                    const float* __restrict__ sim, const int* __restrict__ labels,
                    const int* __restrict__ masks, float* __restrict__ logits,
                    double* __restrict__ accum) {
    const int bidx = blockIdx.x;        // 4 * 32 * 32 = 4096
    const int bb = bidx >> 10;
    const int mt = (bidx >> 5) & 31;
    const int nt = bidx & 31;

    // K tile: 64 rows x 256 bf16 (512 B data), padded to 528 B rows.
    // bank stride per row = 132 dwords % 32 = 4 -> <=2-way conflicts (free).
    __shared__ __align__(16) unsigned short Ks[64][264];

    const int tid  = threadIdx.x;
    const int w    = tid >> 6;     // wave 0..3
    const int lane = tid & 63;
    const int lrow = lane & 15;    // operand-fragment row
    const int lkg  = lane >> 4;    // k-group 0..3 (8 contiguous k each)

    // ---- stage K tile (32 KB) ----
    {
        const unsigned short* kbase = khl + ((size_t)bb * S_ + (size_t)nt * 64) * 256;
#pragma unroll
        for (int it = 0; it < 8; ++it) {
            const int f = it * 256 + tid;        // 0..2047
            const int r = f >> 5;                // row 0..63
            const int ch = f & 31;               // 16B chunk 0..31
            *reinterpret_cast<uint4*>(reinterpret_cast<char*>(&Ks[0][0]) + r * 528 + ch * 16) =
                *reinterpret_cast<const uint4*>(kbase + (size_t)r * 256 + ch * 8);
        }
    }

    // ---- load Q fragments straight from global ----
    // qf[h][p][s]: lane holds q[m0 + lrow][h][p][ s*32 + lkg*8 .. +8 ]
    short8v qf[2][2][2];
    {
        const int mrow = mt * 64 + w * 16 + lrow;
        const unsigned short* qrow = qhl + ((size_t)bb * S_ + mrow) * 256;
#pragma unroll
        for (int h = 0; h < 2; ++h)
#pragma unroll
            for (int p = 0; p < 2; ++p)
#pragma unroll
                for (int s = 0; s < 2; ++s)
                    qf[h][p][s] = *reinterpret_cast<const short8v*>(
                        qrow + h * 128 + p * 64 + s * 32 + lkg * 8);
    }
    __syncthreads();

    // ---- MFMA: wave computes 16(m) x 64(n), both heads ----
    f32x4 acc[2][4];
#pragma unroll
    for (int h = 0; h < 2; ++h)
#pragma unroll
        for (int cg = 0; cg < 4; ++cg)
            acc[h][cg] = (f32x4){0.f, 0.f, 0.f, 0.f};

#pragma unroll
    for (int h = 0; h < 2; ++h) {
#pragma unroll
        for (int cg = 0; cg < 4; ++cg) {
#pragma unroll
            for (int s = 0; s < 2; ++s) {
                const char* krow = reinterpret_cast<const char*>(&Ks[0][0]) +
                                   (cg * 16 + lrow) * 528 +
                                   h * 256 + s * 64 + lkg * 16;
                const short8v kh = *reinterpret_cast<const short8v*>(krow);        // plane hi
                const short8v kl = *reinterpret_cast<const short8v*>(krow + 128);  // plane lo
                acc[h][cg] = __builtin_amdgcn_mfma_f32_16x16x32_bf16(qf[h][0][s], kh, acc[h][cg], 0, 0, 0);
                acc[h][cg] = __builtin_amdgcn_mfma_f32_16x16x32_bf16(qf[h][0][s], kl, acc[h][cg], 0, 0, 0);
                acc[h][cg] = __builtin_amdgcn_mfma_f32_16x16x32_bf16(qf[h][1][s], kh, acc[h][cg], 0, 0, 0);
            }
        }
    }

    // ---- fused epilogue ----
    // C/D layout (m89-verified): col = lane&15, row = (lane>>4)*4 + reg.
    float lsum = 0.f, msum = 0.f;
#pragma unroll
    for (int cg = 0; cg < 4; ++cg) {
        const int n = nt * 64 + cg * 16 + lrow;
#pragma unroll
        for (int r = 0; r < 4; ++r) {
            const int m = mt * 64 + w * 16 + lkg * 4 + r;
            const size_t cell = ((size_t)bb * S_ + m) * S_ + n;
            const float sv = sim[cell];
            const float l0 = acc[0][cg][r] * sv;
            const float l1 = acc[1][cg][r] * sv;
            *reinterpret_cast<float2*>(&logits[cell * 2]) = make_float2(l0, l1);
            const int lab = labels[cell];
            const float mk = (masks[cell] == 1) ? 1.0f : 0.0f;
            const float mx = fmaxf(l0, l1);
            const float mn = fminf(l0, l1);
            const float lse = mx + log1pf(expf(mn - mx));   // == logsumexp(l0,l1)
            const float nll = lse - (lab ? l1 : l0);
            lsum += nll * mk;
            msum += mk;
        }
    }

    // Wave reduce (64 lanes) then cross-wave via LDS, one double atomic per block.
#pragma unroll
    for (int off = 32; off > 0; off >>= 1) {
        lsum += __shfl_down(lsum, off);
        msum += __shfl_down(msum, off);
    }
    __shared__ double wred[8];
    if (lane == 0) {
        wred[w]     = (double)lsum;
        wred[4 + w] = (double)msum;
    }
    __syncthreads();
    if (tid == 0) {
        atomicAdd(&accum[0], wred[0] + wred[1] + wred[2] + wred[3]);
        atomicAdd(&accum[1], wred[4] + wred[5] + wred[6] + wred[7]);
    }
}

__global__ void finalize_kernel(const double* __restrict__ accum, float* __restrict__ out) {
    out[0] = (float)(accum[0] / accum[1]);
}

// ---------------------------------------------------------------------------
extern "C" void kernel_launch(void* const* d_in, const int* in_sizes, int n_in,
                              void* d_out, int out_size, void* d_ws, size_t ws_size,
                              hipStream_t stream) {
    const float* seq    = (const float*)d_in[0];
    const float* W      = (const float*)d_in[1];
    const float* bias   = (const float*)d_in[2];
    const float* sim    = (const float*)d_in[3];
    const int*   labels = (const int*)d_in[4];
    const int*   masks  = (const int*)d_in[5];
    float* out = (float*)d_out;   // out[0] = loss, out[1..] = pred_logits (B,S,S,2)

    double* accum = (double*)d_ws;                                   // 2 doubles
    unsigned short* qhl = (unsigned short*)((char*)d_ws + 256);      // [8192][2][2][64] bf16
    unsigned short* khl = qhl + (size_t)M_ * 256;                    // same, 4 MB each

    hipMemsetAsync(d_ws, 0, 16, stream);

    dim3 gA(M_ / 64, 4);
    gemm1_rope_kernel<<<gA, 256, 0, stream>>>(seq, W, bias, qhl, khl);

    qk_loss_kernel<<<4096, 256, 0, stream>>>(qhl, khl, sim, labels, masks,
                                             out + 1, accum);

    finalize_kernel<<<1, 1, 0, stream>>>(accum, out);
}

// Round 9
// 417.121 us; speedup vs baseline: 1.1958x; 1.1958x over previous
//
#include <hip/hip_runtime.h>
#include <hip/hip_bf16.h>
#include <math.h>

#define B_     4
#define S_     2048
#define D_     1024
#define M_     (B_ * S_)   // 8192

typedef __attribute__((ext_vector_type(8))) short short8v;  // 8 bf16
typedef __attribute__((ext_vector_type(4))) float f32x4;    // MFMA acc

__device__ __forceinline__ unsigned short f32_to_bf16_rne(float f) {
    unsigned u = __float_as_uint(f);
    return (unsigned short)((u + 0x7FFFu + ((u >> 16) & 1u)) >> 16);
}
__device__ __forceinline__ float bf16_to_f32(unsigned short h) {
    return __uint_as_float((unsigned)h << 16);
}

// ---------------------------------------------------------------------------
// Kernel A (MFMA): out = seq @ W^T + bias, RoPE, split -> q/k hi/lo bf16.
// Block = 32 m-rows x 256 j-cols, 8 waves (512 thr): wave w owns m-sub
// (w&1)*16 and j-quarter (w>>1)*64. A-operand = W (j on MFMA row), B = seq
// (m on MFMA col): each lane gets fixed m, 4 consecutive j -> intra-lane
// RoPE pairs. W fp32 -> hi/lo bf16 converted on the fly during staging
// (W is 1 MB, L2/L3-resident across blocks). RoPE via R3-proven
// pow-table + __sincosf. q/k layout: [m][head(2)][plane(2)][d(64)] bf16.
// LDS rows padded to 40 bf16 (80 B): wave64 b128 reads spread uniformly
// over the 8 four-bank groups (5 coprime 8) -> conflict-free.
// ---------------------------------------------------------------------------
__global__ __launch_bounds__(512)
void gemm1_rope_kernel(const float* __restrict__ seq,
                       const float* __restrict__ W,
                       const float* __restrict__ bias,
                       unsigned short* __restrict__ qhl, unsigned short* __restrict__ khl) {
    const int bm = blockIdx.x;            // 256 blocks of 32 rows
    const int tid = threadIdx.x;
    const int w = tid >> 6, lane = tid & 63;
    const int lrow = lane & 15, lkg = lane >> 4;
    const int wm = (w & 1) * 16;          // m-sub
    const int jq = w >> 1;                // j-quarter 0..3 (64 cols each)
    const int m0 = bm * 32;

    __shared__ __align__(16) unsigned short Sh[32][40], Sl[32][40];      // seq hi/lo
    __shared__ __align__(16) unsigned short Wth[256][40], Wtl[256][40];  // W hi/lo
    __shared__ float s_inv[32];           // 15^(-t/32), R3-proven path

    if (tid < 32) s_inv[tid] = (float)pow(15.0, -(double)tid / 32.0);

    f32x4 acc[4];
#pragma unroll
    for (int i = 0; i < 4; ++i) acc[i] = (f32x4){0.f, 0.f, 0.f, 0.f};

    const int srow = tid >> 3, scol = (tid & 7) * 4;   // threads 0..255 stage seq

    for (int k0 = 0; k0 < D_; k0 += 32) {
        // stage seq tile (32 rows x 32 k fp32) with on-the-fly hi/lo conversion
        if (tid < 256) {
            const float4 v = *reinterpret_cast<const float4*>(
                seq + (size_t)(m0 + srow) * D_ + k0 + scol);
            const unsigned short h0 = f32_to_bf16_rne(v.x), h1 = f32_to_bf16_rne(v.y),
                                 h2 = f32_to_bf16_rne(v.z), h3 = f32_to_bf16_rne(v.w);
            *reinterpret_cast<ushort4*>(&Sh[srow][scol]) = make_ushort4(h0, h1, h2, h3);
            *reinterpret_cast<ushort4*>(&Sl[srow][scol]) =
                make_ushort4(f32_to_bf16_rne(v.x - bf16_to_f32(h0)),
                             f32_to_bf16_rne(v.y - bf16_to_f32(h1)),
                             f32_to_bf16_rne(v.z - bf16_to_f32(h2)),
                             f32_to_bf16_rne(v.w - bf16_to_f32(h3)));
        }
        // stage W tile (256 rows x 32 k fp32): 2048 float4, 4 per thread
#pragma unroll
        for (int p = 0; p < 4; ++p) {
            const int c = tid + p * 512;          // 0..2047
            const int j = c >> 3;                 // 0..255
            const int kk = (c & 7) * 4;           // 0,4,...,28
            const float4 v = *reinterpret_cast<const float4*>(
                W + (size_t)j * D_ + k0 + kk);
            const unsigned short h0 = f32_to_bf16_rne(v.x), h1 = f32_to_bf16_rne(v.y),
                                 h2 = f32_to_bf16_rne(v.z), h3 = f32_to_bf16_rne(v.w);
            *reinterpret_cast<ushort4*>(&Wth[j][kk]) = make_ushort4(h0, h1, h2, h3);
            *reinterpret_cast<ushort4*>(&Wtl[j][kk]) =
                make_ushort4(f32_to_bf16_rne(v.x - bf16_to_f32(h0)),
                             f32_to_bf16_rne(v.y - bf16_to_f32(h1)),
                             f32_to_bf16_rne(v.z - bf16_to_f32(h2)),
                             f32_to_bf16_rne(v.w - bf16_to_f32(h3)));
        }
        __syncthreads();

        const short8v sh = *reinterpret_cast<const short8v*>(&Sh[wm + lrow][lkg * 8]);
        const short8v sl = *reinterpret_cast<const short8v*>(&Sl[wm + lrow][lkg * 8]);
#pragma unroll
        for (int cg = 0; cg < 4; ++cg) {
            const int jr = jq * 64 + cg * 16 + lrow;
            const short8v wh = *reinterpret_cast<const short8v*>(&Wth[jr][lkg * 8]);
            const short8v wl = *reinterpret_cast<const short8v*>(&Wtl[jr][lkg * 8]);
            acc[cg] = __builtin_amdgcn_mfma_f32_16x16x32_bf16(wh, sh, acc[cg], 0, 0, 0);
            acc[cg] = __builtin_amdgcn_mfma_f32_16x16x32_bf16(wh, sl, acc[cg], 0, 0, 0);
            acc[cg] = __builtin_amdgcn_mfma_f32_16x16x32_bf16(wl, sh, acc[cg], 0, 0, 0);
        }
        __syncthreads();
    }

    // Epilogue: bias + RoPE (__sincosf, R3-proven at absmax 0.125) + hi/lo store.
    // C/D (R3-pinned): col(lane&15)=m (B=seq row), row(lkg*4+r)=j (A=W row).
    const int m = m0 + wm + lrow;
    const int s = m & (S_ - 1);
#pragma unroll
    for (int cg = 0; cg < 4; ++cg) {
        const int j0 = jq * 64 + cg * 16 + lkg * 4;
        const float4 bv = *reinterpret_cast<const float4*>(bias + j0);
        const float x0 = acc[cg][0] + bv.x, x1 = acc[cg][1] + bv.y;
        const float x2 = acc[cg][2] + bv.z, x3 = acc[cg][3] + bv.w;
        const int h = j0 >> 7;                // head
        const int c = j0 & 127;               // 0..127 within head
        const int d0 = c & 63;                // 0..60, multiple of 4
        float sn0, cs0, sn1, cs1;
        __sincosf((float)s * s_inv[d0 >> 1],       &sn0, &cs0);
        __sincosf((float)s * s_inv[(d0 >> 1) + 1], &sn1, &cs1);
        const float r0 = x0 * cs0 - x1 * sn0;
        const float r1 = x1 * cs0 + x0 * sn0;
        const float r2 = x2 * cs1 - x3 * sn1;
        const float r3 = x3 * cs1 + x2 * sn1;
        const unsigned short a0 = f32_to_bf16_rne(r0), a1 = f32_to_bf16_rne(r1),
                             a2 = f32_to_bf16_rne(r2), a3 = f32_to_bf16_rne(r3);
        unsigned short* dst = (c < 64) ? qhl : khl;
        const size_t base = (size_t)m * 256 + (size_t)h * 128 + d0;
        *reinterpret_cast<ushort4*>(dst + base) = make_ushort4(a0, a1, a2, a3);
        *reinterpret_cast<ushort4*>(dst + base + 64) =
            make_ushort4(f32_to_bf16_rne(r0 - bf16_to_f32(a0)),
                         f32_to_bf16_rne(r1 - bf16_to_f32(a1)),
                         f32_to_bf16_rne(r2 - bf16_to_f32(a2)),
                         f32_to_bf16_rne(r3 - bf16_to_f32(a3)));
    }
}

// ---------------------------------------------------------------------------
// K1: logits[b,m,n,h] = (q·k) * sim. R3-VERBATIM operand order and epilogue
// mapping (A=Q, B=K; col=n, row=m — end-to-end proven in R3's pass), with
// the loss epilogue split out into a separate streaming kernel. Per-(cg,r)
// accesses are coalesced across lanes (16 lanes -> 64B sim / 128B logits).
// ---------------------------------------------------------------------------
__global__ __launch_bounds__(256)
void qk_sim_kernel(const unsigned short* __restrict__ qhl,
                   const unsigned short* __restrict__ khl,
                   const float* __restrict__ sim,
                   float* __restrict__ logits) {
    const int bidx = blockIdx.x;          // 4096
    const int bb = bidx >> 10, mt = (bidx >> 5) & 31, nt = bidx & 31;
    __shared__ __align__(16) unsigned short Ks[64][264];   // 528 B rows, 2-way max

    const int tid = threadIdx.x, w = tid >> 6, lane = tid & 63;
    const int lrow = lane & 15, lkg = lane >> 4;

    // stage K tile (32 KB) — R3-verbatim
    {
        const unsigned short* kbase = khl + ((size_t)bb * S_ + (size_t)nt * 64) * 256;
#pragma unroll
        for (int it = 0; it < 8; ++it) {
            const int f = it * 256 + tid;
            const int r = f >> 5, ch = f & 31;
            *reinterpret_cast<uint4*>(reinterpret_cast<char*>(&Ks[0][0]) + r * 528 + ch * 16) =
                *reinterpret_cast<const uint4*>(kbase + (size_t)r * 256 + ch * 8);
        }
    }

    // Q fragments from global (L2-resident 4 MB) — R3-verbatim
    const int mq = mt * 64 + w * 16 + lrow;
    short8v qf[2][2][2];
    {
        const unsigned short* qrow = qhl + ((size_t)bb * S_ + mq) * 256;
#pragma unroll
        for (int h = 0; h < 2; ++h)
#pragma unroll
            for (int p = 0; p < 2; ++p)
#pragma unroll
                for (int sx = 0; sx < 2; ++sx)
                    qf[h][p][sx] = *reinterpret_cast<const short8v*>(
                        qrow + h * 128 + p * 64 + sx * 32 + lkg * 8);
    }
    __syncthreads();

    f32x4 acc[2][4];
#pragma unroll
    for (int h = 0; h < 2; ++h)
#pragma unroll
        for (int cg = 0; cg < 4; ++cg) acc[h][cg] = (f32x4){0.f, 0.f, 0.f, 0.f};

#pragma unroll
    for (int h = 0; h < 2; ++h)
#pragma unroll
        for (int cg = 0; cg < 4; ++cg)
#pragma unroll
            for (int sx = 0; sx < 2; ++sx) {
                const char* krow = reinterpret_cast<const char*>(&Ks[0][0]) +
                                   (cg * 16 + lrow) * 528 + h * 256 + sx * 64 + lkg * 16;
                const short8v kh = *reinterpret_cast<const short8v*>(krow);
                const short8v kl = *reinterpret_cast<const short8v*>(krow + 128);
                acc[h][cg] = __builtin_amdgcn_mfma_f32_16x16x32_bf16(qf[h][0][sx], kh, acc[h][cg], 0, 0, 0);
                acc[h][cg] = __builtin_amdgcn_mfma_f32_16x16x32_bf16(qf[h][0][sx], kl, acc[h][cg], 0, 0, 0);
                acc[h][cg] = __builtin_amdgcn_mfma_f32_16x16x32_bf16(qf[h][1][sx], kh, acc[h][cg], 0, 0, 0);
            }

    // Epilogue — R3-verbatim mapping: col(lane&15)=n, row(lkg*4+r)=m.
#pragma unroll
    for (int cg = 0; cg < 4; ++cg) {
        const int n = nt * 64 + cg * 16 + lrow;
#pragma unroll
        for (int r = 0; r < 4; ++r) {
            const int m = mt * 64 + w * 16 + lkg * 4 + r;
            const size_t cell = ((size_t)bb * S_ + m) * S_ + n;
            const float sv = sim[cell];
            logits[cell * 2]     = acc[0][cg][r] * sv;
            logits[cell * 2 + 1] = acc[1][cg][r] * sv;
        }
    }
}

// ---------------------------------------------------------------------------
// K2: streaming loss; one cell per thread per iteration, scalar dword loads,
// block-level double atomics.
// ---------------------------------------------------------------------------
__global__ __launch_bounds__(256)
void loss_kernel(const float* __restrict__ logits, const int* __restrict__ labels,
                 const int* __restrict__ masks, double* __restrict__ accum) {
    const size_t NCELL = (size_t)B_ * S_ * S_;            // 16777216
    const size_t stride = (size_t)gridDim.x * blockDim.x;
    float lsum = 0.f, msum = 0.f;
    for (size_t c = (size_t)blockIdx.x * blockDim.x + threadIdx.x; c < NCELL; c += stride) {
        const float l0 = logits[c * 2];
        const float l1 = logits[c * 2 + 1];
        const int lab = labels[c];
        const int mk  = masks[c];
        const float mx = fmaxf(l0, l1), mn = fminf(l0, l1);
        const float lse = mx + log1pf(expf(mn - mx));     // logsumexp(l0,l1)
        const float nll = lse - (lab ? l1 : l0);
        const float mf = (mk == 1) ? 1.0f : 0.0f;
        lsum += nll * mf;
        msum += mf;
    }
#pragma unroll
    for (int off = 32; off > 0; off >>= 1) {
        lsum += __shfl_down(lsum, off);
        msum += __shfl_down(msum, off);
    }
    __shared__ double wred[8];
    const int w = threadIdx.x >> 6;
    if ((threadIdx.x & 63) == 0) { wred[w] = (double)lsum; wred[4 + w] = (double)msum; }
    __syncthreads();
    if (threadIdx.x == 0) {
        atomicAdd(&accum[0], wred[0] + wred[1] + wred[2] + wred[3]);
        atomicAdd(&accum[1], wred[4] + wred[5] + wred[6] + wred[7]);
    }
}

__global__ void finalize_kernel(const double* __restrict__ accum, float* __restrict__ out) {
    out[0] = (float)(accum[0] / accum[1]);
}

// ---------------------------------------------------------------------------
extern "C" void kernel_launch(void* const* d_in, const int* in_sizes, int n_in,
                              void* d_out, int out_size, void* d_ws, size_t ws_size,
                              hipStream_t stream) {
    const float* seq    = (const float*)d_in[0];
    const float* W      = (const float*)d_in[1];
    const float* bias   = (const float*)d_in[2];
    const float* sim    = (const float*)d_in[3];
    const int*   labels = (const int*)d_in[4];
    const int*   masks  = (const int*)d_in[5];
    float* out    = (float*)d_out;        // out[0]=loss, out[1..]=pred_logits
    float* logits = out + 1;

    // ws usage: 256 B + 4 MB + 4 MB = 8.00 MB (<= R3-proven footprint)
    double* accum = (double*)d_ws;
    unsigned short* qhl = (unsigned short*)((char*)d_ws + 256);   // [8192][2][2][64]
    unsigned short* khl = qhl + (size_t)M_ * 256;

    hipMemsetAsync(accum, 0, 16, stream);
    gemm1_rope_kernel<<<256, 512, 0, stream>>>(seq, W, bias, qhl, khl);
    qk_sim_kernel<<<4096, 256, 0, stream>>>(qhl, khl, sim, logits);
    loss_kernel<<<2048, 256, 0, stream>>>(logits, labels, masks, accum);
    finalize_kernel<<<1, 1, 0, stream>>>(accum, out);
}